// Round 13
// baseline (57.626 us; speedup 1.0000x reference)
//
#include <hip/hip_runtime.h>
#include <hip/hip_bf16.h>
#include <cstdint>
#include <cstddef>

// Problem constants
#define BB 64
#define TN 4096
#define FF 128
#define NBLK 256                 // cov blocks: 64 batches x 4 quarters, 1/CU
#define WROWS 256                // t-rows per wave
#define NST 8                    // 8 subtiles (32 rows each) per wave

#define NTILE_UP 36
#define TILE_ELEMS 256
#define PART_FLOATS (NTILE_UP * TILE_ELEMS)   // 9216

#define WREG 9248                // per-wave LDS region bytes (2312 dwords)

// ws layout (floats)
#define SUM0_OFF 0
#define MEAN_OFF (SUM0_OFF + BB * FF)
#define RSTD_OFF (MEAN_OFF + BB * FF)
#define SABS_OFF (RSTD_OFF + BB * FF)
#define TRI_OFF  (SABS_OFF + 1)
#define DONE_OFF (TRI_OFF + 1)
#define ZERO_FLOATS (DONE_OFF + 1)
#define R_OFF 24832                           // [BB][9216]
#define P_OFF (R_OFF + BB * PART_FLOATS)      // [NBLK][9216]  (9.4 MB)

typedef __attribute__((ext_vector_type(8))) short bf16x8_t;
typedef __attribute__((ext_vector_type(4))) short short4_t;
typedef __attribute__((ext_vector_type(4))) float f32x4;

// upper-tri tile index, compile-time foldable (no array, rule #20-safe)
__host__ __device__ constexpr int rbase(int i) { return i * 8 - (i * (i - 1)) / 2; }

// runtime tables for the small follow-up kernels only
__device__ __constant__ int kRowBaseRT[8] = {0, 8, 15, 21, 26, 30, 33, 35};
__device__ __constant__ int kDiagTr[36] = {
    0,-1,-1,-1,-1,-1,-1,-1, 1,-1,-1,-1,-1,-1,-1, 2,-1,-1,-1,-1,-1,
    3,-1,-1,-1,-1, 4,-1,-1,-1, 5,-1,-1, 6,-1, 7};

// packed f32x2 -> bf16x2 (compiler emits v_cvt_pk_bf16_f32; RNE)
static __device__ __forceinline__ unsigned pk2(float lo, float hi) {
    float2 t; t.x = lo; t.y = hi;
    __hip_bfloat162 r = __float22bfloat162_rn(t);
    unsigned u;
    __builtin_memcpy(&u, &r, 4);     // bf162 not trivially copyable: memcpy folds
    return u;
}
static __device__ __forceinline__ float elem(const float4& v, int j) {
    return reinterpret_cast<const float*>(&v)[j];    // j compile-time after unroll
}

// ---------------------------------------------------------------------------
// Kernel 1: wave-private bf16-MFMA syrk. 256 blocks x 256 thr, 1 block/CU.
// NO barriers, NO inline asm. 4 staging sets (A/B/C/D = 32 outstanding
// dwordx4 per wave = 32 KB in flight, 128 KB/CU) so the compiler's counted
// waitcnt leaves 24 loads in flight at each convert. Packed bf16 cvt.
// ---------------------------------------------------------------------------
__global__ __launch_bounds__(256, 1) void cov_kernel(const float* __restrict__ x,
                                                     float* __restrict__ ws)
{
    __shared__ __align__(16) char lds[4 * WREG];   // ~37 KB

    const int b  = blockIdx.x >> 2;
    const int qt = blockIdx.x & 3;
    const int tid  = threadIdx.x;
    const int w    = tid >> 6;
    const int lane = tid & 63;
    const int m    = lane & 15;    // MFMA frag coords
    const int h    = lane >> 4;    // 0..3
    const int c    = lane & 31;    // staging f-quad
    const int hl   = lane >> 5;    // staging row-half

    char* T = lds + w * WREG;
    const float* xw = x + ((size_t)b * TN + qt * 1024 + w * WROWS) * FF;

    f32x4 acc[36];
#pragma unroll
    for (int i = 0; i < 36; ++i) acc[i] = (f32x4){0.f, 0.f, 0.f, 0.f};
    float csum[4] = {0.f, 0.f, 0.f, 0.f};
    float sabs = 0.f;

    float4 A[8], B[8], C[8], D[8];   // four staging sets, static-indexed

    // half hh (0..15): lane loads 8 rows (hh*16 + hl*8 + i) x 16B f-quad c
    auto load = [&](int hh, float4* dst) {
        const char* a = (const char*)xw + (size_t)(hh * 16 + hl * 8) * 512 + c * 16;
#pragma unroll
        for (int i = 0; i < 8; ++i)
            dst[i] = *(const float4*)(a + (size_t)i * 512);
    };

    // kblk kb (0..3): store 8 rows' bf16 at XOR-swizzled 16B column
    auto convert = [&](const float4* s, int kb) {
        const int sw = ((kb ^ (c & 3)) << 4);
#pragma unroll
        for (int j = 0; j < 4; ++j) {
            const float v0 = elem(s[0],j), v1 = elem(s[1],j), v2 = elem(s[2],j),
                        v3 = elem(s[3],j), v4 = elem(s[4],j), v5 = elem(s[5],j),
                        v6 = elem(s[6],j), v7 = elem(s[7],j);
            csum[j] += ((v0+v1)+(v2+v3)) + ((v4+v5)+(v6+v7));
            sabs += ((fabsf(v0)+fabsf(v1))+(fabsf(v2)+fabsf(v3)))
                  + ((fabsf(v4)+fabsf(v5))+(fabsf(v6)+fabsf(v7)));
            char* dst = T + (c * 4 + j) * 72 + sw;
            *(uint2*)dst     = (uint2){pk2(v0, v1), pk2(v2, v3)};
            *(uint2*)(dst+8) = (uint2){pk2(v4, v5), pk2(v6, v7)};
        }
    };

    auto frags_mfma = [&]() {
        bf16x8_t F[8];
#pragma unroll
        for (int i = 0; i < 8; ++i) {
            const char* p = T + (i * 16 + m) * 72 + ((h ^ (m >> 2)) << 4);
            short4_t lo = *(const short4_t*)p;
            short4_t hi = *(const short4_t*)(p + 8);
            F[i] = (bf16x8_t){lo.x,lo.y,lo.z,lo.w,hi.x,hi.y,hi.z,hi.w};
        }
#pragma unroll
        for (int i = 0; i < 8; ++i)
#pragma unroll
            for (int j = i; j < 8; ++j)
                acc[rbase(i) + (j - i)] =
                    __builtin_amdgcn_mfma_f32_16x16x32_bf16(F[i], F[j],
                        acc[rbase(i) + (j - i)], 0, 0, 0);
    };

    // ---- main loop: per wave, zero barriers, 4-deep staging ----
    load(0, A); load(1, B); load(2, C); load(3, D);
#pragma unroll 1
    for (int sp = 0; sp < 4; ++sp) {        // each sp = 2 subtiles
        convert(A, hl);                      // halves 4sp, 4sp+1
        if (sp < 3) load(4 * sp + 4, A);
        convert(B, 2 + hl);
        if (sp < 3) load(4 * sp + 5, B);
        frags_mfma();                        // subtile 2sp

        convert(C, hl);                      // halves 4sp+2, 4sp+3
        if (sp < 3) load(4 * sp + 6, C);
        convert(D, 2 + hl);
        if (sp < 3) load(4 * sp + 7, D);
        frags_mfma();                        // subtile 2sp+1
    }

    // ---- epilogue: column sums + sum|x| ----
#pragma unroll
    for (int j = 0; j < 4; ++j) csum[j] += __shfl_down(csum[j], 32, 64);
#pragma unroll
    for (int off = 32; off > 0; off >>= 1) sabs += __shfl_down(sabs, off, 64);
    __syncthreads();             // all waves done with T
    if (lane < 32) {
#pragma unroll
        for (int j = 0; j < 4; ++j) ((float*)T)[c * 4 + j] = csum[j];
    }
    if (lane == 0) ((float*)T)[128] = sabs;
    __syncthreads();
    if (tid < FF) {
        float s = 0.f;
#pragma unroll
        for (int w4 = 0; w4 < 4; ++w4) s += ((float*)(lds + w4 * WREG))[tid];
        atomicAdd(&ws[SUM0_OFF + b * FF + tid], s);
    }
    if (tid == 0) {
        float s = 0.f;
#pragma unroll
        for (int w4 = 0; w4 < 4; ++w4) s += ((float*)(lds + w4 * WREG))[128];
        atomicAdd(&ws[SABS_OFF], s);
    }

    // ---- epilogue: cross-wave tile reduction, 4 passes x 9 tiles ----
    float* Pb = ws + P_OFF + (size_t)blockIdx.x * PART_FLOATS;
#pragma unroll
    for (int pass = 0; pass < 4; ++pass) {
        __syncthreads();
        float* q = (float*)lds + w * 2312;
#pragma unroll
        for (int tt = 0; tt < 9; ++tt) {
            const int t = pass * 9 + tt;
#pragma unroll
            for (int qq = 0; qq < 4; ++qq)
                q[tt * 256 + (h * 4 + qq) * 16 + m] = acc[t][qq];
        }
        __syncthreads();
#pragma unroll
        for (int e = 0; e < 9; ++e) {
            const int idx = e * 256 + tid;
            float s = 0.f;
#pragma unroll
            for (int w4 = 0; w4 < 4; ++w4) s += ((float*)lds)[w4 * 2312 + idx];
            Pb[pass * 2304 + idx] = s;
        }
    }
}

// ---------------------------------------------------------------------------
// Kernel 2: reduce 4 quarter-partials -> R, fused mean/rstd for diag tiles.
// ---------------------------------------------------------------------------
__global__ __launch_bounds__(256) void reduce_stats_kernel(float* __restrict__ ws)
{
    const int bb = blockIdx.x / NTILE_UP;
    const int t  = blockIdx.x % NTILE_UP;
    const int e  = t * 256 + threadIdx.x;
    const float* P = ws + P_OFF + (size_t)bb * 4 * PART_FLOATS + e;
    const float a = (P[0] + P[PART_FLOATS]) + (P[2*PART_FLOATS] + P[3*PART_FLOATS]);
    ws[R_OFF + (size_t)bb * PART_FLOATS + e] = a;

    const int tr = kDiagTr[t];
    if (tr >= 0) {
        const int i = threadIdx.x >> 4, j = threadIdx.x & 15;
        if (i == j) {
            const int idx = bb * FF + tr * 16 + i;
            const float mean = ws[SUM0_OFF + idx] * (1.f / TN);
            const float var  = a * (1.f / TN) - mean * mean;
            ws[MEAN_OFF + idx] = mean;
            ws[RSTD_OFF + idx] = rsqrtf(fmaxf(var, 1e-30f));
        }
    }
}

// ---------------------------------------------------------------------------
// Kernel 3: corr_avg_abs + strict upper-tri sum; last block writes outputs.
// ---------------------------------------------------------------------------
__global__ __launch_bounds__(256) void corr_final_kernel(float* __restrict__ ws,
                                                         float* __restrict__ out)
{
    __shared__ float red[4];
    const int p = blockIdx.x * 256 + threadIdx.x;   // 0..16383
    const int f = p >> 7, g = p & 127;

    float v = 0.f;
    if (g > f) {
        const int tidx = kRowBaseRT[f >> 4] + ((g >> 4) - (f >> 4));
        const size_t off = (size_t)tidx * TILE_ELEMS + (f & 15) * 16 + (g & 15);
        float accum = 0.f;
#pragma unroll 8
        for (int b = 0; b < BB; ++b) {
            const float s2 = ws[R_OFF + (size_t)b * PART_FLOATS + off];
            const float mf = ws[MEAN_OFF + b * FF + f];
            const float mg = ws[MEAN_OFF + b * FF + g];
            const float rf = ws[RSTD_OFF + b * FF + f];
            const float rg = ws[RSTD_OFF + b * FF + g];
            accum += (s2 * (1.f / TN) - mf * mg) * rf * rg;
        }
        v = fabsf(accum * (1.f / BB));
    }

#pragma unroll
    for (int off = 32; off > 0; off >>= 1) v += __shfl_down(v, off, 64);
    const int lane = threadIdx.x & 63, wid = threadIdx.x >> 6;
    if (lane == 0) red[wid] = v;
    __syncthreads();
    if (threadIdx.x == 0) {
        atomicAdd(&ws[TRI_OFF], (red[0] + red[1]) + (red[2] + red[3]));
        __threadfence();
        const float old = atomicAdd(&ws[DONE_OFF], 1.0f);
        if (old == 63.0f) {                       // last block: publish outputs
            const float tri  = atomicAdd(&ws[TRI_OFF], 0.0f);
            const float sabs = ws[SABS_OFF];
            out[0] = tri * (0.01f / 8128.f);
            out[1] = tri;
            out[2] = sabs * (1.f / FF);
        }
    }
}

extern "C" void kernel_launch(void* const* d_in, const int* in_sizes, int n_in,
                              void* d_out, int out_size, void* d_ws, size_t ws_size,
                              hipStream_t stream)
{
    const float* x = (const float*)d_in[0];
    float* out = (float*)d_out;
    float* ws = (float*)d_ws;

    (void)hipMemsetAsync(d_ws, 0, (size_t)ZERO_FLOATS * sizeof(float), stream);

    hipLaunchKernelGGL(cov_kernel,          dim3(NBLK), dim3(256), 0, stream, x, ws);
    hipLaunchKernelGGL(reduce_stats_kernel, dim3(BB * NTILE_UP), dim3(256), 0, stream, ws);
    hipLaunchKernelGGL(corr_final_kernel,   dim3((FF * FF) / 256), dim3(256), 0, stream, ws, out);
}